// Round 5
// baseline (18395.146 us; speedup 1.0000x reference)
//
#include <hip/hip_runtime.h>

// ---------------------------------------------------------------------------
// RNN scan on MI355X — round 5: hybrid VALU(dot2) + matrix-pipe(MFMA) scan.
//   k in [  0,256): dot2, thread t owns column t. U: 20 quads VGPR + 12 LDS.
//   k in [256,512): mfma_f32_16x16x32_f16, U in B-frag layout in 128 AGPRs
//                   (consumed directly by MFMA -> no v_accvgpr_read moves).
//   A operand = h replicated across rows -> D = y[col] in every lane/reg.
//   Wave w owns c-tiles 4w..4w+3 (cols 64w..64w+63); partial via pm[] LDS.
// ---------------------------------------------------------------------------

#define UVQ 20      // dot2 U quads (uint4) per thread in VGPRs (80 u32)
#define UTQ 12      // dot2 U quads per thread in LDS (48 u32, 96 KB)

typedef _Float16 f16x8 __attribute__((ext_vector_type(8)));
typedef float    f32x4 __attribute__((ext_vector_type(4)));
typedef _Float16 h2_t  __attribute__((ext_vector_type(2)));
union U32H2 { unsigned u; _Float16 f[2]; h2_t h; };
union QU    { uint4 q; unsigned u[4]; _Float16 f[8]; f16x8 v; };

__device__ inline unsigned pkf16(float a, float b){
  U32H2 v; v.f[0]=(_Float16)a; v.f[1]=(_Float16)b; return v.u;
}
__device__ inline float dot2(unsigned a, unsigned b, float c){
  U32H2 x,y; x.u=a; y.u=b;
  return __builtin_amdgcn_fdot2(x.h, y.h, c, false);   // v_dot2_f32_f16
}

// ---------------------------------------------------------------------------
// P: pack weights. 256 blocks x 256 threads (idx < 65536; 3 jobs, idx<16384).
//  (1) Wq[kp4*512+j]: e-th elem = pack(Ww[8kp4+2e][j], Ww[8kp4+2e+1][j])
//  (2) dot2-U quads: (g,t) g<32: elem e = pack(Uw[8g+2e][t], Uw[8g+2e+1][t])
//      g<UVQ -> UVP[g*512+t]; else UTP[(g-UVQ)*512+t]      (k in [0,256))
//  (3) B-frags: (ct,kt,l): elem j: Uw[256+32kt+(l>>4)*8+j][16ct+(l&15)]
//      -> UBF[(ct*8+kt)*64 + l]                             (k in [256,512))
// ---------------------------------------------------------------------------
__global__ __launch_bounds__(256) void prep_pack(const float* __restrict__ Ww,
                                                 const float* __restrict__ Uw,
                                                 uint4* __restrict__ Wq,
                                                 uint4* __restrict__ UVP,
                                                 uint4* __restrict__ UTP,
                                                 uint4* __restrict__ UBF){
  int idx = blockIdx.x*256 + threadIdx.x;
  if (idx < 32*512){ // (1) W pack
    int kp4 = idx >> 9, j = idx & 511;
    QU v;
    #pragma unroll
    for (int e=0;e<4;e++)
      v.u[e] = pkf16(Ww[(8*kp4+2*e)*512 + j], Ww[(8*kp4+2*e+1)*512 + j]);
    Wq[idx] = v.q;
  }
  if (idx < 32*512){ // (2) dot2-U pack
    int g = idx >> 9, t = idx & 511;
    QU v;
    #pragma unroll
    for (int e=0;e<4;e++)
      v.u[e] = pkf16(Uw[(8*g+2*e)*512 + t], Uw[(8*g+2*e+1)*512 + t]);
    if (g < UVQ) UVP[g*512 + t] = v.q;
    else         UTP[(g-UVQ)*512 + t] = v.q;
  }
  if (idx < 32*512){ // (3) MFMA B-frag pack
    int ct = idx >> 9, kt = (idx >> 6) & 7, l = idx & 63;
    QU v;
    #pragma unroll
    for (int j=0;j<8;j++){
      int k = 256 + 32*kt + (l>>4)*8 + j;
      int c = 16*ct + (l&15);
      v.f[j] = (_Float16)Uw[k*512 + c];
    }
    UBF[(ct*8 + kt)*64 + l] = v.q;
  }
}

// ---------------------------------------------------------------------------
// G: wx GEMM (unchanged from R4). Output wxp[(b*2048+s)*256+j] =
// pack(col j, col j+256). 4096 blocks x 256 threads.
// ---------------------------------------------------------------------------
__global__ __launch_bounds__(256) void gemm_wx(const float* __restrict__ x,
                                               const uint4* __restrict__ Wq,
                                               const float* __restrict__ Wb,
                                               unsigned* __restrict__ wxp){
  __shared__ __align__(16) unsigned xt[32][128];   // 16 KB
  const int tid = threadIdx.x;
  const int b = blockIdx.x >> 6, sb = blockIdx.x & 63;
  const float* xrow = x + ((size_t)(b*2048 + sb*32))*256;
  #pragma unroll
  for (int i=0;i<8;i++){
    int f = i*256 + tid;
    int r = f >> 6, c4 = f & 63;
    float4 v = ((const float4*)xrow)[r*64 + c4];
    xt[r][2*c4]   = pkf16(v.x, v.y);
    xt[r][2*c4+1] = pkf16(v.z, v.w);
  }
  float acc0[32], acc1[32];
  #pragma unroll
  for (int r=0;r<32;r++){ acc0[r]=0.f; acc1[r]=0.f; }
  __syncthreads();
  #pragma unroll 2
  for (int kp4=0;kp4<32;kp4++){
    uint4 w0 = Wq[kp4*512 + tid];
    uint4 w1 = Wq[kp4*512 + tid + 256];
    #pragma unroll
    for (int r=0;r<32;r++){
      uint4 xv = *(const uint4*)&xt[r][4*kp4];     // b128 broadcast
      acc0[r] = dot2(w0.w, xv.w, dot2(w0.z, xv.z, dot2(w0.y, xv.y, dot2(w0.x, xv.x, acc0[r]))));
      acc1[r] = dot2(w1.w, xv.w, dot2(w1.z, xv.z, dot2(w1.y, xv.y, dot2(w1.x, xv.x, acc1[r]))));
    }
  }
  float wb0 = Wb[tid], wb1 = Wb[tid+256];
  unsigned* o = wxp + ((size_t)(b*2048 + sb*32))*256;
  #pragma unroll
  for (int r=0;r<32;r++)
    o[r*256 + tid] = pkf16(acc0[r]+wb0, acc1[r]+wb1);
}

// ---------------------------------------------------------------------------
// R: hybrid scan. 64 blocks x 512 threads, 2 waves/EU.
// LDS: utail 96 KB + harr 1 KB + pm 2 KB + rbuf ~ 99.1 KB.
// ---------------------------------------------------------------------------
__global__ __launch_bounds__(512)
__attribute__((amdgpu_waves_per_eu(2,2)))
void rnn_scan(const uint4* __restrict__ UVP,
              const uint4* __restrict__ UTP,
              const uint4* __restrict__ UBF,
              const unsigned* __restrict__ wxp,
              const float* __restrict__ Ub,
              const float* __restrict__ Vw,
              const float* __restrict__ Vb,
              float* __restrict__ out){
  __shared__ __align__(16) _Float16 harr[512];
  __shared__ uint4 utail[UTQ*512];                 // 96 KB
  __shared__ float pm[512];                        // MFMA partials per column
  __shared__ float rbuf[16];
  const int t = threadIdx.x, b = blockIdx.x;
  const int w = t >> 6, l = t & 63;

  uint4 uvq[UVQ];                                  // 80 arch VGPRs
  #pragma unroll
  for (int g=0; g<UVQ; g++) uvq[g] = UVP[g*512 + t];
  #pragma unroll
  for (int i=0; i<UTQ; i++) utail[i*512 + t] = UTP[i*512 + t];
  f16x8 ubf[32];                                   // 128 AGPRs (MFMA B only)
  const f16x8* UBFv = (const f16x8*)UBF;
  #pragma unroll
  for (int i=0; i<4; i++)
    #pragma unroll
    for (int kt=0; kt<8; kt++)
      ubf[i*8+kt] = UBFv[((w*4+i)*8 + kt)*64 + l];

  harr[t] = (_Float16)0.f;                         // h0 = 0
  const float ub_c = Ub[t];
  const unsigned* wxb = wxp + (size_t)b*2048*256;
  const int wxo = t & 255, hi = t >> 8;
  unsigned wc = wxb[wxo], wn = wxb[256 + wxo];
  __syncthreads();

  const uint4* hq = (const uint4*)harr;            // k [0,256) as 32 quads
  const f16x8* hA = (const f16x8*)(harr + 256);    // k [256,512) A-frags
  const int afi = l >> 4;
  float hf = 0.f;

  #pragma unroll 1
  for (int ts=0; ts<2048; ts++){
    U32H2 wv; wv.u = wc;
    wc = wn;
    int tn = (ts+2 < 2048) ? (ts+2) : 2047;
    wn = wxb[tn*256 + wxo];                        // prefetch wx[ts+2]

    // ---- matrix-pipe half: k in [256,512), c-tiles 4w..4w+3 ----
    f32x4 acc0 = {0.f,0.f,0.f,0.f}, acc1 = {0.f,0.f,0.f,0.f};
    f32x4 acc2 = {0.f,0.f,0.f,0.f}, acc3 = {0.f,0.f,0.f,0.f};
    #pragma unroll
    for (int kt=0; kt<8; kt++){
      f16x8 af = hA[kt*4 + afi];                   // h replicated over rows
      acc0 = __builtin_amdgcn_mfma_f32_16x16x32_f16(af, ubf[     kt], acc0, 0,0,0);
      acc1 = __builtin_amdgcn_mfma_f32_16x16x32_f16(af, ubf[ 8 + kt], acc1, 0,0,0);
      acc2 = __builtin_amdgcn_mfma_f32_16x16x32_f16(af, ubf[16 + kt], acc2, 0,0,0);
      acc3 = __builtin_amdgcn_mfma_f32_16x16x32_f16(af, ubf[24 + kt], acc3, 0,0,0);
    }

    // ---- VALU half: k in [0,256), column t ----
    float a0 = (float)wv.f[hi] + ub_c, a1 = 0.f;
    #pragma unroll
    for (int g=0; g<UVQ; g++){
      uint4 hv = hq[g];                            // broadcast b128
      uint4 u  = uvq[g];
      a0 = dot2(u.x, hv.x, a0); a1 = dot2(u.y, hv.y, a1);
      a0 = dot2(u.z, hv.z, a0); a1 = dot2(u.w, hv.w, a1);
    }
    #pragma unroll
    for (int i=0; i<UTQ; i++){
      uint4 hv = hq[UVQ + i];
      uint4 u  = utail[i*512 + t];
      a0 = dot2(u.x, hv.x, a0); a1 = dot2(u.y, hv.y, a1);
      a0 = dot2(u.z, hv.z, a0); a1 = dot2(u.w, hv.w, a1);
    }

    // MFMA readout: every lane/reg of acc_i holds y[64w + 16i + (l&15)]
    if (l < 16){
      int cb = 64*w + l;
      pm[cb     ] = acc0[0];
      pm[cb + 16] = acc1[0];
      pm[cb + 32] = acc2[0];
      pm[cb + 48] = acc3[0];
    }
    __syncthreads();                               // pm ready; h reads done
    float s = a0 + a1 + pm[t];
    hf = 1.f - 2.f/(__expf(2.f*s) + 1.f);          // tanh, saturates cleanly
    harr[t] = (_Float16)hf;
    __syncthreads();                               // h visible for next step
  }

  // epilogue: out[b,:] = sigmoid(h_T @ V + Vb); thread t holds h_T[t]
  float p0 = hf*Vw[2*t], p1 = hf*Vw[2*t+1];
  #pragma unroll
  for (int off=32; off>0; off>>=1){
    p0 += __shfl_down(p0, off);
    p1 += __shfl_down(p1, off);
  }
  if ((t & 63) == 0){
    rbuf[(t>>6)*2]   = p0;
    rbuf[(t>>6)*2+1] = p1;
  }
  __syncthreads();
  if (t == 0){
    float s0 = Vb[0], s1 = Vb[1];
    #pragma unroll
    for (int q=0;q<8;q++){ s0 += rbuf[2*q]; s1 += rbuf[2*q+1]; }
    out[2*b]   = 1.f/(1.f + __expf(-s0));
    out[2*b+1] = 1.f/(1.f + __expf(-s1));
  }
}

// ---------------------------------------------------------------------------
extern "C" void kernel_launch(void* const* d_in, const int* in_sizes, int n_in,
                              void* d_out, int out_size, void* d_ws, size_t ws_size,
                              hipStream_t stream) {
  const float* x  = (const float*)d_in[0];   // [64,2048,256]
  const float* Ww = (const float*)d_in[1];   // [256,512]
  const float* Wb = (const float*)d_in[2];   // [512]
  const float* Uw = (const float*)d_in[3];   // [512,512]
  const float* Ub = (const float*)d_in[4];   // [512]
  const float* Vw = (const float*)d_in[5];   // [512,2]
  const float* Vb = (const float*)d_in[6];   // [2]
  float* out = (float*)d_out;                // [64,2]

  char* ws = (char*)d_ws;
  size_t off = 0;
  unsigned* wxp = (unsigned*)(ws + off); off += 134217728;        // 128 MB
  uint4*    Wq  = (uint4*)(ws + off);    off += (size_t)32*512*16;   // 256 KB
  uint4*    UVP = (uint4*)(ws + off);    off += (size_t)UVQ*512*16;  // 160 KB
  uint4*    UTP = (uint4*)(ws + off);    off += (size_t)UTQ*512*16;  //  96 KB
  uint4*    UBF = (uint4*)(ws + off);    off += (size_t)32*8*64*16;  // 256 KB

  prep_pack<<<256, 256, 0, stream>>>(Ww, Uw, Wq, UVP, UTP, UBF);
  gemm_wx  <<<4096, 256, 0, stream>>>(x, Wq, Wb, wxp);
  rnn_scan <<<64, 512, 0, stream>>>(UVP, UTP, UBF, wxp, Ub, Vw, Vb, out);
}